// Round 2
// baseline (358.575 us; speedup 1.0000x reference)
//
#include <hip/hip_runtime.h>
#include <hip/hip_bf16.h>

#define NREL 5000
#define NBIN 32
#define NEDGE 200000
#define DIM 512
#define NHEAD 8
#define CAP 1024

typedef __attribute__((ext_vector_type(8))) short short8;
typedef __attribute__((ext_vector_type(4))) float f32x4;
typedef unsigned short ushort_t;

__device__ __forceinline__ float b2f(ushort_t u) {
  unsigned int v = ((unsigned int)u) << 16;
  union { unsigned int i; float f; } c; c.i = v; return c.f;
}

// ---------- dtype detection ----------
// flags[0]=1 if float tensors are bf16 on device (else f32)
// flags[1]=1 if relation_triplets is int64 on device (else int32)
__global__ void detect_k(const ushort_t* __restrict__ emb_raw,
                         const int* __restrict__ trip_raw,
                         int* __restrict__ flags) {
  __shared__ int cnt_s, nz_s;
  if (threadIdx.x == 0) { cnt_s = 0; nz_s = 0; }
  __syncthreads();
  int plaus = 0;
  for (int i = threadIdx.x; i < 4096; i += 256) {
    ushort_t u = emb_raw[2 * i];     // even ushort: value if bf16, mantissa-low if f32
    int e = (u >> 7) & 0xFF;
    if (e >= 96 && e <= 159) plaus++;
  }
  atomicAdd(&cnt_s, plaus);
  int nz = 0;
  for (int i = threadIdx.x; i < 2048; i += 256) {
    if (trip_raw[2 * i + 1] != 0) nz++;  // odd word: 0 if int64 (small nonneg vals)
  }
  atomicAdd(&nz_s, nz);
  __syncthreads();
  if (threadIdx.x == 0) {
    flags[0] = (cnt_s >= 3900) ? 1 : 0;
    flags[1] = (nz_s == 0) ? 1 : 0;
  }
}

// canonicalize float tensor -> bf16 (copy if already bf16, RNE-round if f32)
__global__ void convert_f(const void* __restrict__ src, ushort_t* __restrict__ dst,
                          int n, const int* __restrict__ flags) {
  int i = blockIdx.x * blockDim.x + threadIdx.x;
  if (i >= n) return;
  if (flags[0]) {
    dst[i] = ((const ushort_t*)src)[i];
  } else {
    union { float f; unsigned int u; } c;
    c.f = ((const float*)src)[i];
    unsigned int u = c.u;
    unsigned int r = (u + 0x7FFFu + ((u >> 16) & 1u)) >> 16;  // RNE
    dst[i] = (ushort_t)r;
  }
}

// canonicalize triplets -> int32
__global__ void convert_t(const int* __restrict__ src, int* __restrict__ dst,
                          const int* __restrict__ flags) {
  int i = blockIdx.x * blockDim.x + threadIdx.x;
  if (i >= 3 * NEDGE) return;
  dst[i] = flags[1] ? src[2 * i] : src[i];
}

// ---------- OUT[Mrows][512](f32) = A[Mrows][512](bf16) . W-rows(bf16) + bias ----------
__global__ __launch_bounds__(256) void gemm_bt(
    const ushort_t* __restrict__ A, int Mrows,
    const ushort_t* __restrict__ W, int wld, int woff,
    const ushort_t* __restrict__ bias, float* __restrict__ OUT)
{
  int l = threadIdx.x & 63;
  int wv = threadIdx.x >> 6;
  int rt = blockIdx.x * 64 + wv * 16;
  int ct = blockIdx.y * 64;
  int klo = (l >> 4) * 8;
  int rA = rt + (l & 15);
  f32x4 acc[4] = {};
  for (int kk = 0; kk < DIM; kk += 32) {
    short8 a = {};
    if (rA < Mrows)
      a = *(const short8*)(A + rA * DIM + kk + klo);
#pragma unroll
    for (int n = 0; n < 4; ++n) {
      int col = ct + n * 16 + (l & 15);
      short8 b = *(const short8*)(W + col * wld + woff + kk + klo);
      acc[n] = __builtin_amdgcn_mfma_f32_16x16x32_bf16(a, b, acc[n], 0, 0, 0);
    }
  }
  int r0 = rt + (l >> 4) * 4;
#pragma unroll
  for (int n = 0; n < 4; ++n) {
    int col = ct + n * 16 + (l & 15);
    float bv = bias ? b2f(bias[col]) : 0.0f;
#pragma unroll
    for (int j = 0; j < 4; ++j) {
      int row = r0 + j;
      if (row < Mrows) OUT[row * DIM + col] = acc[n][j] + bv;
    }
  }
}

__global__ void count_k(const int* __restrict__ trip, int* __restrict__ cnt) {
  int e = blockIdx.x * blockDim.x + threadIdx.x;
  if (e >= NEDGE) return;
  int h = trip[3 * e]; h = min(max(h, 0), NREL - 1);
  atomicAdd(&cnt[h], 1);
}

__global__ __launch_bounds__(256) void scan_k(const int* __restrict__ cnt, int* __restrict__ off) {
  __shared__ int buf[256];
  __shared__ int carry;
  int t = threadIdx.x;
  if (t == 0) carry = 0;
  __syncthreads();
  for (int base = 0; base < NREL; base += 256) {
    int v = (base + t < NREL) ? cnt[base + t] : 0;
    buf[t] = v;
    __syncthreads();
    for (int d = 1; d < 256; d <<= 1) {
      int x = (t >= d) ? buf[t - d] : 0;
      __syncthreads();
      buf[t] += x;
      __syncthreads();
    }
    if (base + t < NREL) off[base + t] = carry + buf[t] - v;
    __syncthreads();
    if (t == 0) carry += buf[255];
    __syncthreads();
  }
  if (t == 0) off[NREL] = carry;
}

__global__ void scatter_k(const int* __restrict__ trip, const int* __restrict__ off,
                          int* __restrict__ cur, int* __restrict__ eids) {
  int e = blockIdx.x * blockDim.x + threadIdx.x;
  if (e >= NEDGE) return;
  int h = trip[3 * e]; h = min(max(h, 0), NREL - 1);
  int p = atomicAdd(&cur[h], 1);
  eids[off[h] + p] = e;
}

// one block (256 thr) per relation r
__global__ __launch_bounds__(256) void aggr_k(
    const int* __restrict__ trip, const int* __restrict__ off,
    const int* __restrict__ eids,
    const float* __restrict__ P1, const float* __restrict__ P2,
    const float* __restrict__ P3, const float* __restrict__ Mw,
    const ushort_t* __restrict__ avec, float* __restrict__ outf,
    ushort_t* __restrict__ outb, const int* __restrict__ flags)
{
  __shared__ __align__(16) float a_lds[CAP * 8];
  __shared__ int tails[CAP];
  __shared__ __align__(16) float p1row[DIM];
  __shared__ __align__(16) float av[DIM];
  __shared__ float m_s[8], s_s[8], fsc[8], cm_s[8], csum[8];

  int r = blockIdx.x;
  int t = threadIdx.x;
  int l = t & 63, wv = t >> 6;
  int off0 = off[r];
  int nE = off[r + 1] - off0;

  for (int o = t; o < DIM; o += 256) {
    p1row[o] = P1[r * DIM + o];
    av[o] = b2f(avec[o]);
  }
  if (t < 8) { m_s[t] = -INFINITY; s_s[t] = 0.0f; }
  __syncthreads();

  int hd2 = t >> 5;               // head for output pair (2t, 2t+1)
  float accx = 0.0f, accy = 0.0f;
  int hd1 = l >> 3;               // pass1: 8 lanes per head
  int ob = hd1 * 64 + (l & 7) * 8;

  for (int cs = 0; cs < nE; cs += CAP) {
    int ne = min(CAP, nE - cs);
    // ---- pass1: attention logits into LDS ----
    for (int i = wv; i < ne; i += 4) {
      int eid = eids[off0 + cs + i];
      int tail = trip[3 * eid + 1]; tail = min(max(tail, 0), NREL - 1);
      int bin  = trip[3 * eid + 2]; bin  = min(max(bin, 0), NBIN - 1);
      const float4* p2p = (const float4*)(P2 + bin * DIM + ob);
      const float4* p3p = (const float4*)(P3 + (size_t)tail * DIM + ob);
      const float4* p1p = (const float4*)(p1row + ob);
      const float4* avp = (const float4*)(av + ob);
      float part = 0.0f;
#pragma unroll
      for (int q = 0; q < 2; ++q) {
        float4 p2 = p2p[q], p3 = p3p[q], p1 = p1p[q], a4 = avp[q];
        float z;
        z = p1.x + p2.x + p3.x; z = z > 0.f ? z : 0.2f * z; part += z * a4.x;
        z = p1.y + p2.y + p3.y; z = z > 0.f ? z : 0.2f * z; part += z * a4.y;
        z = p1.z + p2.z + p3.z; z = z > 0.f ? z : 0.2f * z; part += z * a4.z;
        z = p1.w + p2.w + p3.w; z = z > 0.f ? z : 0.2f * z; part += z * a4.w;
      }
      part += __shfl_xor(part, 1);
      part += __shfl_xor(part, 2);
      part += __shfl_xor(part, 4);
      if ((l & 7) == 0) a_lds[i * 8 + hd1] = part;
      if (l == 0) tails[i] = tail;
    }
    __syncthreads();
    // ---- chunk max per head ----
    {
      int hd = t >> 5, g = t & 31;
      float mx = -INFINITY;
      for (int i = g; i < ne; i += 32) mx = fmaxf(mx, a_lds[i * 8 + hd]);
      mx = fmaxf(mx, __shfl_xor(mx, 1));
      mx = fmaxf(mx, __shfl_xor(mx, 2));
      mx = fmaxf(mx, __shfl_xor(mx, 4));
      mx = fmaxf(mx, __shfl_xor(mx, 8));
      mx = fmaxf(mx, __shfl_xor(mx, 16));
      if (g == 0) cm_s[hd] = mx;
    }
    __syncthreads();
    if (t < 8) {
      float nm = fmaxf(m_s[t], cm_s[t]);
      fsc[t] = expf(m_s[t] - nm);   // first chunk: exp(-inf)=0
      m_s[t] = nm;
      csum[t] = 0.0f;
    }
    __syncthreads();
    // ---- pass2a: exp + per-head sums ----
    {
      int hd = t & 7;
      float mval = m_s[hd];
      float ps = 0.0f;
      for (int idx = t; idx < ne * 8; idx += 256) {
        float v = expf(a_lds[idx] - mval);
        a_lds[idx] = v;
        ps += v;
      }
      ps += __shfl_xor(ps, 8);
      ps += __shfl_xor(ps, 16);
      ps += __shfl_xor(ps, 32);
      if (l < 8) atomicAdd(&csum[l], ps);
    }
    __syncthreads();
    if (t < 8) s_s[t] = s_s[t] * fsc[t] + csum[t];
    __syncthreads();
    // ---- pass2b: weighted message accumulation ----
    {
      float f = fsc[hd2];
      accx *= f; accy *= f;
      for (int i = 0; i < ne; ++i) {
        float ev = a_lds[i * 8 + hd2];
        const float2* mr = (const float2*)(Mw + (size_t)tails[i] * DIM);
        float2 mv = mr[t];
        accx += ev * mv.x;
        accy += ev * mv.y;
      }
    }
    __syncthreads();
  }
  float inv = 1.0f / (s_s[hd2] + 1e-16f);
  float o0 = accx * inv, o1 = accy * inv;
  if (flags[0]) {
    __hip_bfloat16 b0 = __float2bfloat16(o0);
    __hip_bfloat16 b1 = __float2bfloat16(o1);
    ushort_t u0 = *(ushort_t*)&b0, u1 = *(ushort_t*)&b1;
    ((unsigned int*)outb)[r * 256 + t] = (unsigned int)u0 | ((unsigned int)u1 << 16);
  } else {
    outf[r * DIM + 2 * t] = o0;
    outf[r * DIM + 2 * t + 1] = o1;
  }
}

extern "C" void kernel_launch(void* const* d_in, const int* in_sizes, int n_in,
                              void* d_out, int out_size, void* d_ws, size_t ws_size,
                              hipStream_t stream) {
  // canonical buffer layout in d_ws
  const int REL_N = NREL * DIM;        // 2,560,000
  const int BIN_N = NBIN * DIM;        // 16,384
  const int WATTN_N = DIM * 3 * DIM;   // 786,432
  const int VEC_N = DIM;               // 512
  const int WAGGR_N = DIM * DIM;       // 262,144

  ushort_t* canon = (ushort_t*)d_ws;
  ushort_t* c_rel   = canon;
  ushort_t* c_bin   = c_rel + REL_N;
  ushort_t* c_wattn = c_bin + BIN_N;
  ushort_t* c_battn = c_wattn + WATTN_N;
  ushort_t* c_avec  = c_battn + VEC_N;
  ushort_t* c_waggr = c_avec + VEC_N;
  ushort_t* c_baggr = c_waggr + WAGGR_N;
  ushort_t* c_end   = c_baggr + VEC_N;

  int* trip32 = (int*)c_end;           // 600,000 (c_end is 4B-aligned: even total)
  int* flags  = trip32 + 3 * NEDGE;    // 4
  float* P1 = (float*)(flags + 4);     // 16B-aligned by construction
  float* P2 = P1 + NREL * DIM;
  float* P3 = P2 + NBIN * DIM;
  float* Mw = P3 + NREL * DIM;
  int* cnt  = (int*)(Mw + NREL * DIM);
  int* cur  = cnt + NREL;
  int* off  = cur + NREL;
  int* eids = off + NREL + 1;

  hipMemsetAsync(cnt, 0, 2 * NREL * sizeof(int), stream);  // cnt + cur

  detect_k<<<1, 256, 0, stream>>>((const ushort_t*)d_in[0], (const int*)d_in[2], flags);

  dim3 b1(256);
  convert_f<<<(REL_N + 255) / 256, b1, 0, stream>>>(d_in[0], c_rel, REL_N, flags);
  convert_f<<<(BIN_N + 255) / 256, b1, 0, stream>>>(d_in[1], c_bin, BIN_N, flags);
  convert_f<<<(WATTN_N + 255) / 256, b1, 0, stream>>>(d_in[3], c_wattn, WATTN_N, flags);
  convert_f<<<(VEC_N + 255) / 256, b1, 0, stream>>>(d_in[4], c_battn, VEC_N, flags);
  convert_f<<<(VEC_N + 255) / 256, b1, 0, stream>>>(d_in[5], c_avec, VEC_N, flags);
  convert_f<<<(WAGGR_N + 255) / 256, b1, 0, stream>>>(d_in[6], c_waggr, WAGGR_N, flags);
  convert_f<<<(VEC_N + 255) / 256, b1, 0, stream>>>(d_in[7], c_baggr, VEC_N, flags);
  convert_t<<<(3 * NEDGE + 255) / 256, b1, 0, stream>>>((const int*)d_in[2], trip32, flags);

  dim3 g1((NREL + 63) / 64, DIM / 64);
  dim3 g2(1, DIM / 64);
  gemm_bt<<<g1, b1, 0, stream>>>(c_rel, NREL, c_wattn, 3 * DIM, 0,       nullptr, P1);
  gemm_bt<<<g2, b1, 0, stream>>>(c_bin, NBIN, c_wattn, 3 * DIM, DIM,     c_battn, P2);
  gemm_bt<<<g1, b1, 0, stream>>>(c_rel, NREL, c_wattn, 3 * DIM, 2 * DIM, nullptr, P3);
  gemm_bt<<<g1, b1, 0, stream>>>(c_rel, NREL, c_waggr, DIM,     0,       c_baggr, Mw);

  count_k<<<(NEDGE + 255) / 256, 256, 0, stream>>>(trip32, cnt);
  scan_k<<<1, 256, 0, stream>>>(cnt, off);
  scatter_k<<<(NEDGE + 255) / 256, 256, 0, stream>>>(trip32, off, cur, eids);
  aggr_k<<<NREL, 256, 0, stream>>>(trip32, off, eids, P1, P2, P3, Mw, c_avec,
                                   (float*)d_out, (ushort_t*)d_out, flags);
}

// Round 3
// 249.864 us; speedup vs baseline: 1.4351x; 1.4351x over previous
//
#include <hip/hip_runtime.h>
#include <hip/hip_bf16.h>

#define NREL 5000
#define NBIN 32
#define NEDGE 200000
#define DIM 512
#define NHEAD 8
#define CAP 256

typedef __attribute__((ext_vector_type(8))) short short8;
typedef __attribute__((ext_vector_type(4))) float f32x4;
typedef unsigned short ushort_t;

#define REL_N (NREL * DIM)
#define BIN_N (NBIN * DIM)
#define WATTN_N (DIM * 3 * DIM)
#define VEC_N DIM
#define WAGGR_N (DIM * DIM)

__device__ __forceinline__ float b2f(ushort_t u) {
  unsigned int v = ((unsigned int)u) << 16;
  union { unsigned int i; float f; } c; c.i = v; return c.f;
}
__device__ __forceinline__ ushort_t f2b_rne(float f) {
  union { float f; unsigned int u; } c; c.f = f;
  unsigned int u = c.u;
  return (ushort_t)((u + 0x7FFFu + ((u >> 16) & 1u)) >> 16);
}

// ---------- dtype detection ----------
__global__ void detect_k(const ushort_t* __restrict__ emb_raw,
                         const int* __restrict__ trip_raw,
                         int* __restrict__ flags) {
  __shared__ int cnt_s, nz_s;
  if (threadIdx.x == 0) { cnt_s = 0; nz_s = 0; }
  __syncthreads();
  int plaus = 0;
  for (int i = threadIdx.x; i < 4096; i += 256) {
    ushort_t u = emb_raw[2 * i];
    int e = (u >> 7) & 0xFF;
    if (e >= 96 && e <= 159) plaus++;
  }
  atomicAdd(&cnt_s, plaus);
  int nz = 0;
  for (int i = threadIdx.x; i < 2048; i += 256) {
    if (trip_raw[2 * i + 1] != 0) nz++;
  }
  atomicAdd(&nz_s, nz);
  __syncthreads();
  if (threadIdx.x == 0) {
    flags[0] = (cnt_s >= 3900) ? 1 : 0;
    flags[1] = (nz_s == 0) ? 1 : 0;
  }
}

// ---------- canonicalize all float tensors -> bf16 (one kernel) ----------
__global__ void conv_all(const void* __restrict__ s_rel, const void* __restrict__ s_bin,
                         const void* __restrict__ s_wattn, const void* __restrict__ s_battn,
                         const void* __restrict__ s_avec, const void* __restrict__ s_waggr,
                         const void* __restrict__ s_baggr, ushort_t* __restrict__ dst,
                         const int* __restrict__ flags) {
  const int O1 = REL_N, O2 = O1 + BIN_N, O3 = O2 + WATTN_N, O4 = O3 + VEC_N,
            O5 = O4 + VEC_N, O6 = O5 + WAGGR_N, O7 = O6 + VEC_N;
  int i = blockIdx.x * 256 + threadIdx.x;
  if (i >= O7) return;
  const void* src; int j;
  if (i < O1)      { src = s_rel;   j = i; }
  else if (i < O2) { src = s_bin;   j = i - O1; }
  else if (i < O3) { src = s_wattn; j = i - O2; }
  else if (i < O4) { src = s_battn; j = i - O3; }
  else if (i < O5) { src = s_avec;  j = i - O4; }
  else if (i < O6) { src = s_waggr; j = i - O5; }
  else             { src = s_baggr; j = i - O6; }
  dst[i] = flags[0] ? ((const ushort_t*)src)[j] : f2b_rne(((const float*)src)[j]);
}

// ---------- triplets -> int32 (clamped) + head count ----------
__global__ void convt_count(const int* __restrict__ src, int* __restrict__ dst,
                            int* __restrict__ cnt, const int* __restrict__ flags) {
  int e = blockIdx.x * blockDim.x + threadIdx.x;
  if (e >= NEDGE) return;
  int h, ta, bi;
  if (flags[1]) { h = src[6 * e]; ta = src[6 * e + 2]; bi = src[6 * e + 4]; }
  else          { h = src[3 * e]; ta = src[3 * e + 1]; bi = src[3 * e + 2]; }
  h  = min(max(h, 0), NREL - 1);
  ta = min(max(ta, 0), NREL - 1);
  bi = min(max(bi, 0), NBIN - 1);
  dst[3 * e] = h; dst[3 * e + 1] = ta; dst[3 * e + 2] = bi;
  atomicAdd(&cnt[h], 1);
}

// ---------- fast single-block exclusive scan over 5000 counts ----------
__global__ __launch_bounds__(256) void scan_k(const int* __restrict__ cnt, int* __restrict__ off) {
  __shared__ int wsum[4];
  int t = threadIdx.x, l = t & 63, w = t >> 6;
  int base = t * 20;
  int vals[20];
  int s = 0;
#pragma unroll
  for (int j = 0; j < 20; ++j) {
    int v = (base + j < NREL) ? cnt[base + j] : 0;
    vals[j] = s; s += v;
  }
  int x = s;
#pragma unroll
  for (int d = 1; d < 64; d <<= 1) {
    int y = __shfl_up(x, d, 64);
    if (l >= d) x += y;
  }
  if (l == 63) wsum[w] = x;
  __syncthreads();
  int woff = 0;
  for (int k = 0; k < 4; ++k) if (k < w) woff += wsum[k];
  int thr_excl = woff + x - s;
#pragma unroll
  for (int j = 0; j < 20; ++j)
    if (base + j < NREL) off[base + j] = thr_excl + vals[j];
  if (t == 255) off[NREL] = woff + x;
}

__global__ void scatter_k(const int* __restrict__ trip, const int* __restrict__ off,
                          int* __restrict__ cur, int* __restrict__ eids) {
  int e = blockIdx.x * blockDim.x + threadIdx.x;
  if (e >= NEDGE) return;
  int h = trip[3 * e];
  int p = atomicAdd(&cur[h], 1);
  eids[off[h] + p] = e;
}

// ---------- fused GEMMs: z=0:P1(f32) 1:P3(f32) 2:Mw(bf16,+b_aggr) 3:P2(f32,+b_attn) ----------
__global__ __launch_bounds__(256) void gemm_all(
    const ushort_t* __restrict__ c_rel, const ushort_t* __restrict__ c_bin,
    const ushort_t* __restrict__ c_wattn, const ushort_t* __restrict__ c_battn,
    const ushort_t* __restrict__ c_waggr, const ushort_t* __restrict__ c_baggr,
    float* __restrict__ P1, float* __restrict__ P2, float* __restrict__ P3,
    ushort_t* __restrict__ Mw)
{
  int z = blockIdx.z;
  if (z == 3 && blockIdx.x > 0) return;
  const ushort_t* A = (z == 3) ? c_bin : c_rel;
  int Mrows = (z == 3) ? NBIN : NREL;
  const ushort_t* W = (z == 2) ? c_waggr : c_wattn;
  int wld = (z == 2) ? DIM : 3 * DIM;
  int woff = (z == 1) ? 2 * DIM : ((z == 3) ? DIM : 0);
  const ushort_t* bias = (z == 2) ? c_baggr : ((z == 3) ? c_battn : nullptr);
  float* OUTF = (z == 0) ? P1 : ((z == 1) ? P3 : P2);

  int l = threadIdx.x & 63;
  int wv = threadIdx.x >> 6;
  int rt = blockIdx.x * 64 + wv * 16;
  int ct = blockIdx.y * 64;
  int klo = (l >> 4) * 8;
  int rA = rt + (l & 15);
  f32x4 acc[4] = {};
  for (int kk = 0; kk < DIM; kk += 32) {
    short8 a = {};
    if (rA < Mrows)
      a = *(const short8*)(A + rA * DIM + kk + klo);
#pragma unroll
    for (int n = 0; n < 4; ++n) {
      int col = ct + n * 16 + (l & 15);
      short8 b = *(const short8*)(W + col * wld + woff + kk + klo);
      acc[n] = __builtin_amdgcn_mfma_f32_16x16x32_bf16(a, b, acc[n], 0, 0, 0);
    }
  }
  int r0 = rt + (l >> 4) * 4;
#pragma unroll
  for (int n = 0; n < 4; ++n) {
    int col = ct + n * 16 + (l & 15);
    float bv = bias ? b2f(bias[col]) : 0.0f;
#pragma unroll
    for (int j = 0; j < 4; ++j) {
      int row = r0 + j;
      if (row >= Mrows) continue;
      float v = acc[n][j] + bv;
      if (z == 2) Mw[(size_t)row * DIM + col] = f2b_rne(v);
      else        OUTF[(size_t)row * DIM + col] = v;
    }
  }
}

// ---------- aggregation: one block (256 thr) per relation ----------
__global__ __launch_bounds__(256, 4) void aggr_k(
    const int* __restrict__ trip, const int* __restrict__ off,
    const int* __restrict__ eids,
    const float* __restrict__ P1, const float* __restrict__ P2,
    const float* __restrict__ P3, const ushort_t* __restrict__ Mw,
    const ushort_t* __restrict__ avec, float* __restrict__ outf,
    ushort_t* __restrict__ outb, const int* __restrict__ flags)
{
  __shared__ __align__(16) float a_lds[CAP * 8];   // logits -> ev; reused as reduce buf
  __shared__ int tails[CAP];
  __shared__ float m_s[8], s_s[8], fsc[8], cm_s[8], csum[8];

  int r = blockIdx.x;
  int t = threadIdx.x;
  int l = t & 63, wv = t >> 6;
  int off0 = off[r];
  int nE = off[r + 1] - off0;

  int hd1 = l >> 3;                 // head owned by this lane (8 lanes/head)
  int ob = hd1 * 64 + (l & 7) * 8;  // pass1 dim block

  // hoist per-lane P1/avec slices to registers
  float p1v[8], avv[8];
#pragma unroll
  for (int j = 0; j < 8; ++j) {
    p1v[j] = P1[r * DIM + ob + j];
    avv[j] = b2f(avec[ob + j]);
  }
  // pass2b: lane covers dims [8l, 8l+8) -> head = l>>3 = hd1
  float acc[8] = {};

  if (t < 8) { m_s[t] = -INFINITY; s_s[t] = 0.0f; }
  __syncthreads();

  for (int cs = 0; cs < nE; cs += CAP) {
    int ne = min(CAP, nE - cs);
    // ---- pass1: attention logits ----
    for (int i = wv; i < ne; i += 4) {
      int eid = eids[off0 + cs + i];
      int tail = trip[3 * eid + 1];
      int bin  = trip[3 * eid + 2];
      const float4* p2p = (const float4*)(P2 + bin * DIM + ob);
      const float4* p3p = (const float4*)(P3 + (size_t)tail * DIM + ob);
      float part = 0.0f;
#pragma unroll
      for (int q = 0; q < 2; ++q) {
        float4 p2 = p2p[q], p3 = p3p[q];
#pragma unroll
        for (int j = 0; j < 4; ++j) {
          float z = p1v[q * 4 + j] + ((const float*)&p2)[j] + ((const float*)&p3)[j];
          z = z > 0.f ? z : 0.2f * z;
          part += z * avv[q * 4 + j];
        }
      }
      part += __shfl_xor(part, 1);
      part += __shfl_xor(part, 2);
      part += __shfl_xor(part, 4);
      if ((l & 7) == 0) a_lds[i * 8 + hd1] = part;
      if (l == 0) tails[i] = tail;
    }
    __syncthreads();
    // ---- chunk max per head ----
    {
      int hd = t >> 5, g = t & 31;
      float mx = -INFINITY;
      for (int i = g; i < ne; i += 32) mx = fmaxf(mx, a_lds[i * 8 + hd]);
      mx = fmaxf(mx, __shfl_xor(mx, 1));
      mx = fmaxf(mx, __shfl_xor(mx, 2));
      mx = fmaxf(mx, __shfl_xor(mx, 4));
      mx = fmaxf(mx, __shfl_xor(mx, 8));
      mx = fmaxf(mx, __shfl_xor(mx, 16));
      if (g == 0) cm_s[hd] = mx;
    }
    __syncthreads();
    if (t < 8) {
      float nm = fmaxf(m_s[t], cm_s[t]);
      fsc[t] = expf(m_s[t] - nm);
      m_s[t] = nm;
      csum[t] = 0.0f;
    }
    __syncthreads();
    // ---- pass2a: exp + per-head sums ----
    {
      int hd = t & 7;
      float mval = m_s[hd];
      float ps = 0.0f;
      for (int idx = t; idx < ne * 8; idx += 256) {
        float v = expf(a_lds[idx] - mval);
        a_lds[idx] = v;
        ps += v;
      }
      ps += __shfl_xor(ps, 8);
      ps += __shfl_xor(ps, 16);
      ps += __shfl_xor(ps, 32);
      if (l < 8) atomicAdd(&csum[l], ps);
    }
    __syncthreads();
    if (t < 8) s_s[t] = s_s[t] * fsc[t] + csum[t];
    __syncthreads();
    // ---- pass2b: wave-parallel weighted message accumulation ----
    {
      float f = fsc[hd1];
#pragma unroll
      for (int j = 0; j < 8; ++j) acc[j] *= f;
      for (int i = wv; i < ne; i += 4) {
        float ev = a_lds[i * 8 + hd1];
        short8 mv = *(const short8*)(Mw + (size_t)tails[i] * DIM + 8 * l);
#pragma unroll
        for (int j = 0; j < 8; ++j)
          acc[j] += ev * b2f((ushort_t)mv[j]);
      }
    }
    __syncthreads();
  }
  // ---- cross-wave reduce (reuse a_lds: 4 waves x 512 dims) ----
#pragma unroll
  for (int j = 0; j < 8; ++j) a_lds[wv * DIM + 8 * l + j] = acc[j];
  __syncthreads();
  int d0 = 2 * t;
  float sx = a_lds[d0]       + a_lds[DIM + d0]       + a_lds[2 * DIM + d0]       + a_lds[3 * DIM + d0];
  float sy = a_lds[d0 + 1]   + a_lds[DIM + d0 + 1]   + a_lds[2 * DIM + d0 + 1]   + a_lds[3 * DIM + d0 + 1];
  float inv = 1.0f / (s_s[t >> 5] + 1e-16f);
  float o0 = sx * inv, o1 = sy * inv;
  if (flags[0]) {
    unsigned int u0 = f2b_rne(o0), u1 = f2b_rne(o1);
    ((unsigned int*)outb)[r * 256 + t] = u0 | (u1 << 16);
  } else {
    outf[r * DIM + d0] = o0;
    outf[r * DIM + d0 + 1] = o1;
  }
}

extern "C" void kernel_launch(void* const* d_in, const int* in_sizes, int n_in,
                              void* d_out, int out_size, void* d_ws, size_t ws_size,
                              hipStream_t stream) {
  ushort_t* canon = (ushort_t*)d_ws;
  ushort_t* c_rel   = canon;
  ushort_t* c_bin   = c_rel + REL_N;
  ushort_t* c_wattn = c_bin + BIN_N;
  ushort_t* c_battn = c_wattn + WATTN_N;
  ushort_t* c_avec  = c_battn + VEC_N;
  ushort_t* c_waggr = c_avec + VEC_N;
  ushort_t* c_baggr = c_waggr + WAGGR_N;
  ushort_t* c_end   = c_baggr + VEC_N;

  int* trip32 = (int*)c_end;
  int* flags  = trip32 + 3 * NEDGE;
  float* P1 = (float*)(flags + 4);
  float* P2 = P1 + NREL * DIM;
  float* P3 = P2 + NBIN * DIM;
  ushort_t* Mw = (ushort_t*)(P3 + NREL * DIM);
  int* cnt  = (int*)(Mw + NREL * DIM);
  int* cur  = cnt + NREL;
  int* off  = cur + NREL;
  int* eids = off + NREL + 1;

  hipMemsetAsync(cnt, 0, 2 * NREL * sizeof(int), stream);  // cnt + cur

  detect_k<<<1, 256, 0, stream>>>((const ushort_t*)d_in[0], (const int*)d_in[2], flags);

  const int TOT = REL_N + BIN_N + WATTN_N + 3 * VEC_N + WAGGR_N;
  conv_all<<<(TOT + 255) / 256, 256, 0, stream>>>(d_in[0], d_in[1], d_in[3], d_in[4],
                                                  d_in[5], d_in[6], d_in[7], canon, flags);
  convt_count<<<(NEDGE + 255) / 256, 256, 0, stream>>>((const int*)d_in[2], trip32, cnt, flags);
  scan_k<<<1, 256, 0, stream>>>(cnt, off);
  scatter_k<<<(NEDGE + 255) / 256, 256, 0, stream>>>(trip32, off, cur, eids);

  dim3 gg((NREL + 63) / 64, DIM / 64, 4);
  gemm_all<<<gg, 256, 0, stream>>>(c_rel, c_bin, c_wattn, c_battn, c_waggr, c_baggr,
                                   P1, P2, P3, Mw);

  aggr_k<<<NREL, 256, 0, stream>>>(trip32, off, eids, P1, P2, P3, Mw, c_avec,
                                   (float*)d_out, (ushort_t*)d_out, flags);
}